// Round 14
// baseline (68.286 us; speedup 1.0000x reference)
//
#include <hip/hip_runtime.h>

#define P_SZ 1152
#define DP 8
#define DS 16
#define NTHR 512
#define PT 9             // p's per thread per b: p = r*128 + pq
#define NW 8             // waves per block

// R13 champion (67.5 us) + float4 LDS reduce round + permlane16 xor16.
//   Structure frozen: quad layout (thread (pq,jq) owns
//   u_hat[b][p=r*128+pq][j=jq+4*jj], 72 uh regs, 2 b's); vacc trick
//   (b_logits = (sum v_tau).uh recomputed in softmax pass); s=bid&31
//   mapping (proven optimal R10 both directions); sched_barrier(0) spill
//   guard; rcp/sqrt/exp2 fast intrinsics; iter-0 sums folded into build;
//   DPP quad_perm xor1/xor2 + row_ror4/8 + permlane32_swap (R12/R13);
//   cap (512,4), 2 blocks/CU.
// R14 deltas:
//   - LDS reduce round re-laid out as [buf][ww][b][jq] float4 (jj packed):
//     writes become 1 ds_write_b128 per (b), reads 1 ds_read_b128 per
//     (ww,b) -> ~150 fewer LDS issues/thread across the 3 rounds.
//   - xor16 in quadred -> v_permlane16_swap (odd<->even 16-row swap; sum
//     of the two outputs = xor16 butterfly on the VALU pipe). Guarded by
//     __has_builtin; falls back to __shfl_xor. Commutative -> bit-identical.
//   - v_pk_fma_f32 evaluated and REJECTED: 157.3 TF spec = scalar SIMD-32
//     full rate (m07: 103 TF scalar measured), so packed fp32 on CDNA4 is
//     issue-equivalent, not 2x like CDNA2/3.
__device__ __forceinline__ float qxor1_add(float v) {
    const int t = __builtin_amdgcn_update_dpp(0, __float_as_int(v),
                                              0xB1, 0xF, 0xF, true);
    return v + __int_as_float(t);
}
__device__ __forceinline__ float qxor2_add(float v) {
    const int t = __builtin_amdgcn_update_dpp(0, __float_as_int(v),
                                              0x4E, 0xF, 0xF, true);
    return v + __int_as_float(t);
}
__device__ __forceinline__ float ror4_add(float v) {
    const int t = __builtin_amdgcn_update_dpp(0, __float_as_int(v),
                                              0x124, 0xF, 0xF, true);
    return v + __int_as_float(t);
}
__device__ __forceinline__ float ror8_add(float v) {
    const int t = __builtin_amdgcn_update_dpp(0, __float_as_int(v),
                                              0x128, 0xF, 0xF, true);
    return v + __int_as_float(t);
}
__device__ __forceinline__ float x16_add(float v) {
#if defined(__has_builtin)
#if __has_builtin(__builtin_amdgcn_permlane16_swap)
    const unsigned u = __float_as_uint(v);
    auto p = __builtin_amdgcn_permlane16_swap(u, u, false, false);
    return __uint_as_float(p[0]) + __uint_as_float(p[1]);
#else
    return v + __shfl_xor(v, 16);
#endif
#else
    return v + __shfl_xor(v, 16);
#endif
}
__device__ __forceinline__ float x32_add(float v) {
    const unsigned u = __float_as_uint(v);
    auto p = __builtin_amdgcn_permlane32_swap(u, u, false, false);
    return __uint_as_float(p[0]) + __uint_as_float(p[1]);
}
// full cross-quad reduce (sums the 16 quads; valid in lanes 0-3 at least)
__device__ __forceinline__ float quadred(float v) {
    v = ror4_add(v);
    v = ror8_add(v);
    v = x16_add(v);
    return x32_add(v);
}

__global__ __launch_bounds__(NTHR, 4)
void caps_routing16(const float* __restrict__ x, const float* __restrict__ W,
                    float* __restrict__ out) {
    __shared__ float4 redv[2][NW][2][4];   // [buf][wave][b][jq] -> jj packed in float4
    __shared__ float  rede[2][NW][2];      // [buf][wave][b] esum partials

    const int t    = threadIdx.x;
    const int lane = t & 63;
    const int jq   = t & 3;
    const int pq   = t >> 2;
    const int w    = t >> 6;
    const int bid  = blockIdx.x;
    const int s    = bid & 31;            // 4 W-slices per XCD L2
    const int b0   = (bid >> 5) << 1;

    float uh0[PT][4], uh1[PT][4];
    float sv0[4], sv1[4];
    #pragma unroll
    for (int jj = 0; jj < 4; ++jj) { sv0[jj] = 0.f; sv1[jj] = 0.f; }

    const float* xb0 = x + (size_t)b0 * (P_SZ * DP);
    const float* xb1 = xb0 + P_SZ * DP;

    // ---- build u_hat (iter-0 partial sums folded in) ----
    #pragma unroll
    for (int r = 0; r < PT; ++r) {
        const int p = (r << 7) + pq;
        const float* wp = W + (size_t)(s * P_SZ + p) * (DS * DP) + jq * DP;
        const float4 xa0 = *(const float4*)(xb0 + p * DP);
        const float4 xa1 = *(const float4*)(xb0 + p * DP + 4);
        const float4 xc0 = *(const float4*)(xb1 + p * DP);
        const float4 xc1 = *(const float4*)(xb1 + p * DP + 4);
        #pragma unroll
        for (int jj = 0; jj < 4; ++jj) {   // j = jq + 4*jj
            const float4 w0 = *(const float4*)(wp + jj * 32);
            const float4 w1 = *(const float4*)(wp + jj * 32 + 4);
            uh0[r][jj] = w0.x*xa0.x + w0.y*xa0.y + w0.z*xa0.z + w0.w*xa0.w
                       + w1.x*xa1.x + w1.y*xa1.y + w1.z*xa1.z + w1.w*xa1.w;
            uh1[r][jj] = w0.x*xc0.x + w0.y*xc0.y + w0.z*xc0.z + w0.w*xc0.w
                       + w1.x*xc1.x + w1.y*xc1.y + w1.z*xc1.z + w1.w*xc1.w;
            sv0[jj] += uh0[r][jj];
            sv1[jj] += uh1[r][jj];
        }
        __builtin_amdgcn_sched_barrier(0);   // cap in-flight loads at 1 iter
    }

    // ---------------- iteration 0: c = 1/P ----------------
    #pragma unroll
    for (int jj = 0; jj < 4; ++jj) {
        sv0[jj] = quadred(sv0[jj]);
        sv1[jj] = quadred(sv1[jj]);
    }
    if (lane < 4) {
        redv[0][w][0][lane] = make_float4(sv0[0], sv0[1], sv0[2], sv0[3]);
        redv[0][w][1][lane] = make_float4(sv1[0], sv1[1], sv1[2], sv1[3]);
    }
    __syncthreads();
    #pragma unroll
    for (int jj = 0; jj < 4; ++jj) { sv0[jj] = 0.f; sv1[jj] = 0.f; }
    #pragma unroll
    for (int ww = 0; ww < NW; ++ww) {
        const float4 a = redv[0][ww][0][jq];   // broadcast b128 reads
        const float4 c = redv[0][ww][1][jq];
        sv0[0] += a.x; sv0[1] += a.y; sv0[2] += a.z; sv0[3] += a.w;
        sv1[0] += c.x; sv1[1] += c.y; sv1[2] += c.z; sv1[3] += c.w;
    }
    #pragma unroll
    for (int jj = 0; jj < 4; ++jj) { sv0[jj] *= (1.f / P_SZ); sv1[jj] *= (1.f / P_SZ); }

    float sq0 = sv0[0]*sv0[0] + sv0[1]*sv0[1] + sv0[2]*sv0[2] + sv0[3]*sv0[3];
    float sq1 = sv1[0]*sv1[0] + sv1[1]*sv1[1] + sv1[2]*sv1[2] + sv1[3]*sv1[3];
    sq0 = qxor2_add(qxor1_add(sq0));
    sq1 = qxor2_add(qxor1_add(sq1));
    float f0 = sq0 * __builtin_amdgcn_rcpf(
        (1.f + sq0) * (__builtin_amdgcn_sqrtf(sq0) + 1e-7f));
    float f1 = sq1 * __builtin_amdgcn_rcpf(
        (1.f + sq1) * (__builtin_amdgcn_sqrtf(sq1) + 1e-7f));
    // vacc = accumulated v across iterations (replaces b_logits entirely)
    float va0[4], va1[4];
    #pragma unroll
    for (int jj = 0; jj < 4; ++jj) { va0[jj] = f0 * sv0[jj]; va1[jj] = f1 * sv1[jj]; }

    const float LOG2E = 1.4426950408889634f;

    // ---------------- iterations 1, 2 ----------------
    #pragma unroll
    for (int it = 1; it < 3; ++it) {
        float es0 = 0.f, es1 = 0.f;
        float vas0[4], vas1[4];
        #pragma unroll
        for (int jj = 0; jj < 4; ++jj) {
            vas0[jj] = va0[jj] * LOG2E; vas1[jj] = va1[jj] * LOG2E;
            sv0[jj] = 0.f; sv1[jj] = 0.f;
        }
        // fused: logit (= vacc . uh, DPP quad-reduced) -> exp2 -> num+denom
        #pragma unroll
        for (int r = 0; r < PT; ++r) {
            float d0 = vas0[0]*uh0[r][0] + vas0[1]*uh0[r][1]
                     + vas0[2]*uh0[r][2] + vas0[3]*uh0[r][3];
            float d1 = vas1[0]*uh1[r][0] + vas1[1]*uh1[r][1]
                     + vas1[2]*uh1[r][2] + vas1[3]*uh1[r][3];
            d0 = qxor2_add(qxor1_add(d0));
            d1 = qxor2_add(qxor1_add(d1));
            const float e0 = __builtin_amdgcn_exp2f(d0);
            const float e1 = __builtin_amdgcn_exp2f(d1);
            es0 += e0; es1 += e1;
            #pragma unroll
            for (int jj = 0; jj < 4; ++jj) {
                sv0[jj] += e0 * uh0[r][jj];
                sv1[jj] += e1 * uh1[r][jj];
            }
        }
        // cross-quad reduce (10 values), VALU-pipe
        es0 = quadred(es0);
        es1 = quadred(es1);
        #pragma unroll
        for (int jj = 0; jj < 4; ++jj) {
            sv0[jj] = quadred(sv0[jj]);
            sv1[jj] = quadred(sv1[jj]);
        }
        const int buf = it & 1;
        if (lane < 4) {
            redv[buf][w][0][lane] = make_float4(sv0[0], sv0[1], sv0[2], sv0[3]);
            redv[buf][w][1][lane] = make_float4(sv1[0], sv1[1], sv1[2], sv1[3]);
            if (lane == 0) { rede[buf][w][0] = es0; rede[buf][w][1] = es1; }
        }
        __syncthreads();
        es0 = 0.f; es1 = 0.f;
        #pragma unroll
        for (int jj = 0; jj < 4; ++jj) { sv0[jj] = 0.f; sv1[jj] = 0.f; }
        #pragma unroll
        for (int ww = 0; ww < NW; ++ww) {
            es0 += rede[buf][ww][0];
            es1 += rede[buf][ww][1];
            const float4 a = redv[buf][ww][0][jq];
            const float4 c = redv[buf][ww][1][jq];
            sv0[0] += a.x; sv0[1] += a.y; sv0[2] += a.z; sv0[3] += a.w;
            sv1[0] += c.x; sv1[1] += c.y; sv1[2] += c.z; sv1[3] += c.w;
        }
        const float r0 = __builtin_amdgcn_rcpf(es0);
        const float r1 = __builtin_amdgcn_rcpf(es1);
        #pragma unroll
        for (int jj = 0; jj < 4; ++jj) { sv0[jj] *= r0; sv1[jj] *= r1; }

        sq0 = sv0[0]*sv0[0] + sv0[1]*sv0[1] + sv0[2]*sv0[2] + sv0[3]*sv0[3];
        sq1 = sv1[0]*sv1[0] + sv1[1]*sv1[1] + sv1[2]*sv1[2] + sv1[3]*sv1[3];
        sq0 = qxor2_add(qxor1_add(sq0));
        sq1 = qxor2_add(qxor1_add(sq1));
        f0 = sq0 * __builtin_amdgcn_rcpf(
            (1.f + sq0) * (__builtin_amdgcn_sqrtf(sq0) + 1e-7f));
        f1 = sq1 * __builtin_amdgcn_rcpf(
            (1.f + sq1) * (__builtin_amdgcn_sqrtf(sq1) + 1e-7f));

        if (it == 2) {
            if (t < 4) {
                #pragma unroll
                for (int jj = 0; jj < 4; ++jj)
                    out[(size_t)(b0 * 32 + s) * DS + jq + 4*jj] = f0 * sv0[jj];
            } else if (t < 8) {
                #pragma unroll
                for (int jj = 0; jj < 4; ++jj)
                    out[(size_t)((b0 + 1) * 32 + s) * DS + jq + 4*jj] = f1 * sv1[jj];
            }
        } else {
            #pragma unroll
            for (int jj = 0; jj < 4; ++jj) {
                va0[jj] += f0 * sv0[jj];
                va1[jj] += f1 * sv1[jj];
            }
        }
    }
}

extern "C" void kernel_launch(void* const* d_in, const int* in_sizes, int n_in,
                              void* d_out, int out_size, void* d_ws, size_t ws_size,
                              hipStream_t stream) {
    const float* x = (const float*)d_in[0];   // (128, 1152, 8) fp32
    const float* W = (const float*)d_in[1];   // (32, 1152, 16, 8) fp32
    float* out = (float*)d_out;               // (128, 32, 16) fp32
    caps_routing16<<<dim3(32 * 64), dim3(NTHR), 0, stream>>>(x, W, out);
}

// Round 15
// 67.399 us; speedup vs baseline: 1.0132x; 1.0132x over previous
//
#include <hip/hip_runtime.h>

#define P_SZ 1152
#define DP 8
#define DS 16
#define NTHR 512
#define PT 9             // p's per thread per b: p = r*128 + pq
#define NW 8             // waves per block

// R13 champion (67.5 us) byte-for-byte, + ONE isolated delta: xor16 via
// v_permlane16_swap (guarded). R14's float4 LDS-reduce layout is REVERTED:
// it forced 4-consecutive-VGPR tuples at peak pressure -> 12.5 MB scratch
// (WRITE_SIZE tripwire) and a net regression.
//   Structure frozen: quad layout (thread (pq,jq) owns
//   u_hat[b][p=r*128+pq][j=jq+4*jj], 72 uh regs, 2 b's); vacc trick
//   (b_logits = (sum v_tau).uh recomputed in softmax pass); s=bid&31
//   mapping (proven optimal R10 both directions); sched_barrier(0) spill
//   guard; rcp/sqrt/exp2 fast intrinsics; iter-0 sums folded into build;
//   DPP quad_perm xor1/xor2 + row_ror4/8 + permlane32_swap; scalar LDS
//   reduce round (float4 version spills); cap (512,4), 2 blocks/CU.
__device__ __forceinline__ float qxor1_add(float v) {
    const int t = __builtin_amdgcn_update_dpp(0, __float_as_int(v),
                                              0xB1, 0xF, 0xF, true);
    return v + __int_as_float(t);
}
__device__ __forceinline__ float qxor2_add(float v) {
    const int t = __builtin_amdgcn_update_dpp(0, __float_as_int(v),
                                              0x4E, 0xF, 0xF, true);
    return v + __int_as_float(t);
}
__device__ __forceinline__ float ror4_add(float v) {
    const int t = __builtin_amdgcn_update_dpp(0, __float_as_int(v),
                                              0x124, 0xF, 0xF, true);
    return v + __int_as_float(t);
}
__device__ __forceinline__ float ror8_add(float v) {
    const int t = __builtin_amdgcn_update_dpp(0, __float_as_int(v),
                                              0x128, 0xF, 0xF, true);
    return v + __int_as_float(t);
}
__device__ __forceinline__ float x16_add(float v) {
#if defined(__has_builtin)
#if __has_builtin(__builtin_amdgcn_permlane16_swap)
    const unsigned u = __float_as_uint(v);
    auto p = __builtin_amdgcn_permlane16_swap(u, u, false, false);
    return __uint_as_float(p[0]) + __uint_as_float(p[1]);
#else
    return v + __shfl_xor(v, 16);
#endif
#else
    return v + __shfl_xor(v, 16);
#endif
}
__device__ __forceinline__ float x32_add(float v) {
    const unsigned u = __float_as_uint(v);
    auto p = __builtin_amdgcn_permlane32_swap(u, u, false, false);
    return __uint_as_float(p[0]) + __uint_as_float(p[1]);
}
// full cross-quad reduce (sums the 16 quads; valid in lanes 0-3 at least)
__device__ __forceinline__ float quadred(float v) {
    v = ror4_add(v);
    v = ror8_add(v);
    v = x16_add(v);
    return x32_add(v);
}

__global__ __launch_bounds__(NTHR, 4)
void caps_routing17(const float* __restrict__ x, const float* __restrict__ W,
                    float* __restrict__ out) {
    __shared__ float red[2][NW][2][17];   // [buf][wave][b][j=0..15, 16=esum]

    const int t    = threadIdx.x;
    const int lane = t & 63;
    const int jq   = t & 3;
    const int pq   = t >> 2;
    const int w    = t >> 6;
    const int bid  = blockIdx.x;
    const int s    = bid & 31;            // 4 W-slices per XCD L2
    const int b0   = (bid >> 5) << 1;

    float uh0[PT][4], uh1[PT][4];
    float sv0[4], sv1[4];
    #pragma unroll
    for (int jj = 0; jj < 4; ++jj) { sv0[jj] = 0.f; sv1[jj] = 0.f; }

    const float* xb0 = x + (size_t)b0 * (P_SZ * DP);
    const float* xb1 = xb0 + P_SZ * DP;

    // ---- build u_hat (iter-0 partial sums folded in) ----
    #pragma unroll
    for (int r = 0; r < PT; ++r) {
        const int p = (r << 7) + pq;
        const float* wp = W + (size_t)(s * P_SZ + p) * (DS * DP) + jq * DP;
        const float4 xa0 = *(const float4*)(xb0 + p * DP);
        const float4 xa1 = *(const float4*)(xb0 + p * DP + 4);
        const float4 xc0 = *(const float4*)(xb1 + p * DP);
        const float4 xc1 = *(const float4*)(xb1 + p * DP + 4);
        #pragma unroll
        for (int jj = 0; jj < 4; ++jj) {   // j = jq + 4*jj
            const float4 w0 = *(const float4*)(wp + jj * 32);
            const float4 w1 = *(const float4*)(wp + jj * 32 + 4);
            uh0[r][jj] = w0.x*xa0.x + w0.y*xa0.y + w0.z*xa0.z + w0.w*xa0.w
                       + w1.x*xa1.x + w1.y*xa1.y + w1.z*xa1.z + w1.w*xa1.w;
            uh1[r][jj] = w0.x*xc0.x + w0.y*xc0.y + w0.z*xc0.z + w0.w*xc0.w
                       + w1.x*xc1.x + w1.y*xc1.y + w1.z*xc1.z + w1.w*xc1.w;
            sv0[jj] += uh0[r][jj];
            sv1[jj] += uh1[r][jj];
        }
        __builtin_amdgcn_sched_barrier(0);   // cap in-flight loads at 1 iter
    }

    // ---------------- iteration 0: c = 1/P ----------------
    #pragma unroll
    for (int jj = 0; jj < 4; ++jj) {
        sv0[jj] = quadred(sv0[jj]);
        sv1[jj] = quadred(sv1[jj]);
    }
    if (lane < 4) {
        #pragma unroll
        for (int jj = 0; jj < 4; ++jj) {
            red[0][w][0][jq + 4*jj] = sv0[jj];
            red[0][w][1][jq + 4*jj] = sv1[jj];
        }
    }
    __syncthreads();
    #pragma unroll
    for (int jj = 0; jj < 4; ++jj) { sv0[jj] = 0.f; sv1[jj] = 0.f; }
    #pragma unroll
    for (int ww = 0; ww < NW; ++ww) {
        #pragma unroll
        for (int jj = 0; jj < 4; ++jj) {
            sv0[jj] += red[0][ww][0][jq + 4*jj];   // same-address broadcast reads
            sv1[jj] += red[0][ww][1][jq + 4*jj];
        }
    }
    #pragma unroll
    for (int jj = 0; jj < 4; ++jj) { sv0[jj] *= (1.f / P_SZ); sv1[jj] *= (1.f / P_SZ); }

    float sq0 = sv0[0]*sv0[0] + sv0[1]*sv0[1] + sv0[2]*sv0[2] + sv0[3]*sv0[3];
    float sq1 = sv1[0]*sv1[0] + sv1[1]*sv1[1] + sv1[2]*sv1[2] + sv1[3]*sv1[3];
    sq0 = qxor2_add(qxor1_add(sq0));
    sq1 = qxor2_add(qxor1_add(sq1));
    float f0 = sq0 * __builtin_amdgcn_rcpf(
        (1.f + sq0) * (__builtin_amdgcn_sqrtf(sq0) + 1e-7f));
    float f1 = sq1 * __builtin_amdgcn_rcpf(
        (1.f + sq1) * (__builtin_amdgcn_sqrtf(sq1) + 1e-7f));
    // vacc = accumulated v across iterations (replaces b_logits entirely)
    float va0[4], va1[4];
    #pragma unroll
    for (int jj = 0; jj < 4; ++jj) { va0[jj] = f0 * sv0[jj]; va1[jj] = f1 * sv1[jj]; }

    const float LOG2E = 1.4426950408889634f;

    // ---------------- iterations 1, 2 ----------------
    #pragma unroll
    for (int it = 1; it < 3; ++it) {
        float es0 = 0.f, es1 = 0.f;
        float vas0[4], vas1[4];
        #pragma unroll
        for (int jj = 0; jj < 4; ++jj) {
            vas0[jj] = va0[jj] * LOG2E; vas1[jj] = va1[jj] * LOG2E;
            sv0[jj] = 0.f; sv1[jj] = 0.f;
        }
        // fused: logit (= vacc . uh, DPP quad-reduced) -> exp2 -> num+denom
        #pragma unroll
        for (int r = 0; r < PT; ++r) {
            float d0 = vas0[0]*uh0[r][0] + vas0[1]*uh0[r][1]
                     + vas0[2]*uh0[r][2] + vas0[3]*uh0[r][3];
            float d1 = vas1[0]*uh1[r][0] + vas1[1]*uh1[r][1]
                     + vas1[2]*uh1[r][2] + vas1[3]*uh1[r][3];
            d0 = qxor2_add(qxor1_add(d0));
            d1 = qxor2_add(qxor1_add(d1));
            const float e0 = __builtin_amdgcn_exp2f(d0);
            const float e1 = __builtin_amdgcn_exp2f(d1);
            es0 += e0; es1 += e1;
            #pragma unroll
            for (int jj = 0; jj < 4; ++jj) {
                sv0[jj] += e0 * uh0[r][jj];
                sv1[jj] += e1 * uh1[r][jj];
            }
        }
        // cross-quad reduce (10 values), VALU-pipe
        es0 = quadred(es0);
        es1 = quadred(es1);
        #pragma unroll
        for (int jj = 0; jj < 4; ++jj) {
            sv0[jj] = quadred(sv0[jj]);
            sv1[jj] = quadred(sv1[jj]);
        }
        const int buf = it & 1;
        if (lane < 4) {
            #pragma unroll
            for (int jj = 0; jj < 4; ++jj) {
                red[buf][w][0][jq + 4*jj] = sv0[jj];
                red[buf][w][1][jq + 4*jj] = sv1[jj];
            }
            if (lane == 0) { red[buf][w][0][16] = es0; red[buf][w][1][16] = es1; }
        }
        __syncthreads();
        es0 = 0.f; es1 = 0.f;
        #pragma unroll
        for (int jj = 0; jj < 4; ++jj) { sv0[jj] = 0.f; sv1[jj] = 0.f; }
        #pragma unroll
        for (int ww = 0; ww < NW; ++ww) {
            es0 += red[buf][ww][0][16];
            es1 += red[buf][ww][1][16];
            #pragma unroll
            for (int jj = 0; jj < 4; ++jj) {
                sv0[jj] += red[buf][ww][0][jq + 4*jj];
                sv1[jj] += red[buf][ww][1][jq + 4*jj];
            }
        }
        const float r0 = __builtin_amdgcn_rcpf(es0);
        const float r1 = __builtin_amdgcn_rcpf(es1);
        #pragma unroll
        for (int jj = 0; jj < 4; ++jj) { sv0[jj] *= r0; sv1[jj] *= r1; }

        sq0 = sv0[0]*sv0[0] + sv0[1]*sv0[1] + sv0[2]*sv0[2] + sv0[3]*sv0[3];
        sq1 = sv1[0]*sv1[0] + sv1[1]*sv1[1] + sv1[2]*sv1[2] + sv1[3]*sv1[3];
        sq0 = qxor2_add(qxor1_add(sq0));
        sq1 = qxor2_add(qxor1_add(sq1));
        f0 = sq0 * __builtin_amdgcn_rcpf(
            (1.f + sq0) * (__builtin_amdgcn_sqrtf(sq0) + 1e-7f));
        f1 = sq1 * __builtin_amdgcn_rcpf(
            (1.f + sq1) * (__builtin_amdgcn_sqrtf(sq1) + 1e-7f));

        if (it == 2) {
            if (t < 4) {
                #pragma unroll
                for (int jj = 0; jj < 4; ++jj)
                    out[(size_t)(b0 * 32 + s) * DS + jq + 4*jj] = f0 * sv0[jj];
            } else if (t < 8) {
                #pragma unroll
                for (int jj = 0; jj < 4; ++jj)
                    out[(size_t)((b0 + 1) * 32 + s) * DS + jq + 4*jj] = f1 * sv1[jj];
            }
        } else {
            #pragma unroll
            for (int jj = 0; jj < 4; ++jj) {
                va0[jj] += f0 * sv0[jj];
                va1[jj] += f1 * sv1[jj];
            }
        }
    }
}

extern "C" void kernel_launch(void* const* d_in, const int* in_sizes, int n_in,
                              void* d_out, int out_size, void* d_ws, size_t ws_size,
                              hipStream_t stream) {
    const float* x = (const float*)d_in[0];   // (128, 1152, 8) fp32
    const float* W = (const float*)d_in[1];   // (32, 1152, 16, 8) fp32
    float* out = (float*)d_out;               // (128, 32, 16) fp32
    caps_routing17<<<dim3(32 * 64), dim3(NTHR), 0, stream>>>(x, W, out);
}